// Round 1
// 86.868 us; speedup vs baseline: 1.0126x; 1.0126x over previous
//
#include <hip/hip_runtime.h>
#include <math.h>

#define MESH 4194304
#define NBLOCKS 2048
#define NTHREADS 256
#define QPG 2    // quads per thread: 2048 blk * 4 waves * 64 lanes * 2 quads * 4 elem == MESH
#define NMOM 5   // moments m_0..m_4 of (earg-0.5); K=4 Taylor, abs err ~120 << 9.5e4
#define NVALS (2 + NMOM)  // lv, ls, m[0..4]
#define PMSTRIDE 8

// Pass A: single read of inputs. Per-block partials:
// pm[blk][0]=sum vols, [1]=sum vols^2, [2+k]=sum w*(earg-0.5)^k (k=0..4).
// Key identity (rotation-free): deformed_j . deformed_{j+1}
//   = cos(delta)*(s_j.s_{j+1}) + sin(delta)*(s_j x s_{j+1}),
//   delta = theta_eff[j+1]-theta_eff[j],  and w_j = |delta| (same quantity!).
//
// launch_bounds (256,4): (256,8) capped VGPRs at 64 and the hoisted
// 6xfloat4 + 8-way-unrolled sincos body demands ~80-100 -> scratch spills
// made this streaming kernel ~5x slower than BW roofline. 4 waves/EU
// (16/CU) is ample TLP: ~6 KB loads in flight per wave >> the ~9 KB/CU
// needed to cover HBM latency.
__global__ __launch_bounds__(NTHREADS, 4)
void passA_kernel(const float* __restrict__ theta,
                  const float* __restrict__ statef,
                  float* __restrict__ pm) {
  const int tid = threadIdx.x;
  const int lane = tid & 63, wid = tid >> 6;
  const int wbase = (blockIdx.x * 4 + wid) << 9;  // wave's first element

  // ---- hoisted vector loads (layout verified R3..R7) ----
  float4 tf[QPG], sA[QPG], sB[QPG];
  #pragma unroll
  for (int g = 0; g < QPG; ++g) {
    const int e0 = wbase + (g << 8) + (lane << 2);
    if (e0 != MESH - 4) {
      tf[g] = *(const float4*)(theta + e0);        // theta_eff[e0+1..e0+4]
    } else {                                        // no 4B overread; wrap angle = 0
      tf[g] = make_float4(theta[e0], theta[e0 + 1], theta[e0 + 2], 0.f);
    }
    sA[g] = *(const float4*)(statef + 2 * e0);
    sB[g] = *(const float4*)(statef + 2 * e0 + 4);
  }
  float th_carry = 0.f;
  if (lane == 0 && wbase > 0) th_carry = theta[wbase - 1];
  float2 s_carry = make_float2(0.f, 0.f);
  if (lane == 63) {
    const int en = (wbase + 512 == MESH) ? 0 : wbase + 512;
    s_carry = make_float2(statef[2 * en], statef[2 * en + 1]);
  }

  float vals[NVALS];
  #pragma unroll
  for (int i = 0; i < NVALS; ++i) vals[i] = 0.f;

  #pragma unroll
  for (int g = 0; g < QPG; ++g) {
    const int e0 = wbase + (g << 8) + (lane << 2);
    const float prevw = (g == 0) ? th_carry : __shfl(tf[g - 1].w, 63);
    float th0 = __shfl_up(tf[g].w, 1);
    if (lane == 0) th0 = prevw;
    const float bx = (g + 1 < QPG) ? __shfl(sA[g + 1].x, 0) : s_carry.x;
    const float by = (g + 1 < QPG) ? __shfl(sA[g + 1].y, 0) : s_carry.y;
    float nx = __shfl_down(sA[g].x, 1);
    float ny = __shfl_down(sA[g].y, 1);
    if (lane == 63) { nx = bx; ny = by; }

    const float thseq[5] = {th0, tf[g].x, tf[g].y, tf[g].z, tf[g].w};
    const float sx[5] = {sA[g].x, sA[g].z, sB[g].x, sB[g].z, nx};
    const float sy[5] = {sA[g].y, sA[g].w, sB[g].y, sB[g].w, ny};

    #pragma unroll
    for (int j = 0; j < 4; ++j) {
      const float delta = thseq[j + 1] - thseq[j];
      const float w = fabsf(delta);                       // weight == |delta|
      float sd, cd;
      __sincosf(delta, &sd, &cd);
      const float dotr = sx[j] * sx[j + 1] + sy[j] * sy[j + 1];
      const float crossr = sy[j] * sx[j + 1] - sx[j] * sy[j + 1];
      const float dot = cd * dotr + sd * crossr;          // rotation-free dot
      const float v2s = 1.f - dot * dot;
      const float v2 = fabsf(v2s);
      const float vol = sqrtf(v2);
      vals[0] += vol;   // loss_v partial
      vals[1] += v2;    // loss_s partial
      // e==M-1: exp-arg is signed 1-dot^2 (no sqrt/abs, per reference)
      const float earg = (e0 == MESH - 4 && j == 3) ? v2s : vol;
      const float t = earg - 0.5f;
      float pw = w;
      #pragma unroll
      for (int k = 0; k < NMOM; ++k) {  // m_k += w * t^k
        vals[2 + k] += pw;
        pw *= t;
      }
    }
  }

  // ---- block reduce all 7 values ----
  __shared__ float red[4][NVALS];
  #pragma unroll
  for (int i = 0; i < NVALS; ++i) {
    float v = vals[i];
    #pragma unroll
    for (int off = 32; off > 0; off >>= 1) v += __shfl_down(v, off);
    if (lane == 0) red[wid][i] = v;
  }
  __syncthreads();
  if (tid < NVALS) {
    pm[blockIdx.x * PMSTRIDE + tid] =
        red[0][tid] + red[1][tid] + red[2][tid] + red[3][tid];
  }
}

// Final: reduce 2048 partial rows in f64, rebuild loss_so2 from moments.
__global__ void final_kernel(const float* __restrict__ pm, float* __restrict__ out) {
  double acc[NVALS];
  #pragma unroll
  for (int i = 0; i < NVALS; ++i) acc[i] = 0.0;
  for (int r = threadIdx.x; r < NBLOCKS; r += NTHREADS) {
    const float* row = pm + r * PMSTRIDE;
    #pragma unroll
    for (int i = 0; i < NVALS; ++i) acc[i] += (double)row[i];
  }
  #pragma unroll
  for (int i = 0; i < NVALS; ++i) {
    #pragma unroll
    for (int off = 32; off > 0; off >>= 1) acc[i] += __shfl_down(acc[i], off);
  }
  __shared__ double red[4][NVALS];
  const int lane = threadIdx.x & 63, wid = threadIdx.x >> 6;
  if (lane == 0) {
    #pragma unroll
    for (int i = 0; i < NVALS; ++i) red[wid][i] = acc[i];
  }
  __syncthreads();
  if (threadIdx.x == 0) {
    double t[NVALS];
    #pragma unroll
    for (int i = 0; i < NVALS; ++i)
      t[i] = red[0][i] + red[1][i] + red[2][i] + red[3][i];
    const double lv = t[0], ls = t[1];
    const double a = fabs(lv) / (double)MESH;
    // loss_so2 = e^{-0.5/a} * sum_k m_k * (-1/a)^k / k!
    const double r = -1.0 / a;
    double ck = 1.0, so2 = 0.0;
    #pragma unroll
    for (int k = 0; k < NMOM; ++k) {
      so2 += t[2 + k] * ck;
      ck *= r / (double)(k + 1);
    }
    so2 *= exp(-0.5 / a);
    out[0] = (float)(lv + ls + so2);
  }
}

extern "C" void kernel_launch(void* const* d_in, const int* in_sizes, int n_in,
                              void* d_out, int out_size, void* d_ws, size_t ws_size,
                              hipStream_t stream) {
  const float* theta  = (const float*)d_in[0];   // (MESH-1,) f32
  const float* statef = (const float*)d_in[1];   // (MESH, 2) f32 flat
  float* out = (float*)d_out;
  float* pm = (float*)d_ws;  // pm[2048][8] floats = 64 KB

  passA_kernel<<<NBLOCKS, NTHREADS, 0, stream>>>(theta, statef, pm);
  final_kernel<<<1, NTHREADS, 0, stream>>>(pm, out);
}